// Round 4
// baseline (183.533 us; speedup 1.0000x reference)
//
#include <hip/hip_runtime.h>
#include <hip/hip_bf16.h>

#define N_NODES 50000
#define N_EDGES 312500
#define WIDTH   256
#define LN_EPS  1e-5f
#define RECW    64      // ints per node record: [cnt | 63 src slots] = 256B
#define SLOTS   63      // capacity; degrees ~Poisson(6.25), max ~30
#define GEMM_BLKS 196   // 196 blocks x 256 rows = 50176 >= 50000
#define POISON_I  ((int)0xAAAAAAAAu)  // harness re-poisons d_ws to 0xAA before EVERY
                                      // launch (documented contract) -> cnt baseline

typedef __attribute__((ext_vector_type(8))) short bf16x8;
typedef __attribute__((ext_vector_type(4))) float f32x4;

__device__ __forceinline__ float bf_lo(unsigned u) { return __uint_as_float(u << 16); }
__device__ __forceinline__ float bf_hi(unsigned u) { return __uint_as_float(u & 0xffff0000u); }

__device__ __forceinline__ bf16x8 cvt8(float4 a, float4 b) {
    union { __hip_bfloat16 hh[8]; bf16x8 v; } u;
    u.hh[0] = __float2bfloat16(a.x); u.hh[1] = __float2bfloat16(a.y);
    u.hh[2] = __float2bfloat16(a.z); u.hh[3] = __float2bfloat16(a.w);
    u.hh[4] = __float2bfloat16(b.x); u.hh[5] = __float2bfloat16(b.y);
    u.hh[6] = __float2bfloat16(b.z); u.hh[7] = __float2bfloat16(b.w);
    return u.v;
}

__device__ __forceinline__ ushort4 pack4(f32x4 a) {
    union { __hip_bfloat16 hh[4]; ushort4 v; } u;
    u.hh[0] = __float2bfloat16(a[0]); u.hh[1] = __float2bfloat16(a[1]);
    u.hh[2] = __float2bfloat16(a[2]); u.hh[3] = __float2bfloat16(a[3]);
    return u.v;
}

// ---------------------------------------------------------------------------
// ATTRIBUTION ROUND (R4): the combo dispatch sat at an invariant ~46us across
// THREE structures (R0 64x128-2buf / R1 W-resident / R3 padded-rec fill) with
// all pipes <25% -- two theories falsified, per-component timing unknown.
// This round splits fill / gemm / gather into separate dispatches so rocprof
// reports per-kernel durations. fill_rec drops the 128KiB LDS allocation it
// inherited from the combo (fill blocks were pinning whole CUs); gemm now has
// 196 blocks <= 256 CUs = exactly one scheduling round.
// ---------------------------------------------------------------------------

// ---------------- bucket fill: 4 edges/thread, ILP 4, no LDS ----------------
__global__ __launch_bounds__(256) void fill_rec(const int* __restrict__ src,
                                                const int* __restrict__ dst,
                                                int* __restrict__ rec) {
    int gid = blockIdx.x * 256 + threadIdx.x;
    if (gid < N_EDGES / 4) {                // 312500 = 4*78125 exactly
        int4 d4 = *(const int4*)(dst + gid * 4);
        int4 s4 = *(const int4*)(src + gid * 4);
        int dd[4] = {d4.x, d4.y, d4.z, d4.w};
        int ss[4] = {s4.x, s4.y, s4.z, s4.w};
        #pragma unroll
        for (int u = 0; u < 4; u++) {
            int pos = atomicAdd(&rec[dd[u] * RECW], 1) - POISON_I;  // rebase poison
            rec[dd[u] * RECW + 1 + min(pos, SLOTS - 1)] = ss[u];
        }
    }
}

// ---------------- GEMM: 256 rows x 256 cols per block ----------------
// W resident in LDS as bf16 (128 KiB), staged once, ONE barrier, zero
// barriers in K-loop; x streamed global->reg with 1-step prefetch.
// Structure unchanged from R3 for clean A/B vs combo.
__global__ __launch_bounds__(1024, 4) void gemm(const float* __restrict__ x,
                                                const float* __restrict__ W,
                                                __hip_bfloat16* __restrict__ h) {
    const int blk = blockIdx.x;
    const int t   = threadIdx.x;
    __shared__ short Wl[65536];
    const int lane = t & 63;
    const int wv   = t >> 6;               // 0..15
    const int wr   = wv & 7;               // row strip (32 rows)
    const int wc   = wv >> 3;              // col half (128 cols)
    const int r    = lane & 15;
    const int q    = lane >> 4;
    const int xr   = (r & 7) << 4;         // read-side XOR (n&7 == r&7)

    // issue s=0 x prefetch BEFORE W staging (hide HBM latency under stage)
    const int m0 = blk * 256 + wr * 32;
    const int g0 = min(m0 + r,      N_NODES - 1);   // clamp; garbage never stored
    const int g1 = min(m0 + 16 + r, N_NODES - 1);
    const float* xp0 = x + (size_t)g0 * WIDTH + q * 8;
    const float* xp1 = x + (size_t)g1 * WIDTH + q * 8;
    float4 a00 = *(const float4*)xp0;
    float4 a01 = *(const float4*)(xp0 + 4);
    float4 a10 = *(const float4*)xp1;
    float4 a11 = *(const float4*)(xp1 + 4);

    // ---- stage W -> LDS (bf16, swizzled). 64 floats/thread, 8 iters. ----
    #pragma unroll
    for (int it = 0; it < 8; it++) {
        int f0 = (it * 1024 + t) * 8;      // linear float index = n*256 + k
        int n  = f0 >> 8;
        int k0 = f0 & 255;
        const float* wp = W + f0;
        float4 wa = *(const float4*)wp;
        float4 wb = *(const float4*)(wp + 4);
        int off = (n * 512 + k0 * 2) ^ ((n & 7) << 4);   // full-offset XOR: safe
        *(bf16x8*)((char*)Wl + off) = cvt8(wa, wb);
    }
    __syncthreads();                        // the ONLY barrier

    f32x4 acc[2][8];
    #pragma unroll
    for (int i = 0; i < 2; i++)
        #pragma unroll
        for (int j = 0; j < 8; j++)
            #pragma unroll
            for (int rr = 0; rr < 4; rr++) acc[i][j][rr] = 0.0f;

    // + r*512, + wc*65536 are multiples of 512 -> adding AFTER the bits-4..6
    // XOR cannot carry; j*8192 likewise.
    const char* wbase = (const char*)Wl + wc * 65536 + r * 512;

    #pragma unroll
    for (int s = 0; s < 8; s++) {
        bf16x8 af0 = cvt8(a00, a01);
        bf16x8 af1 = cvt8(a10, a11);
        if (s < 7) {                        // prefetch next k-step
            const float* p0 = xp0 + (s + 1) * 32;
            const float* p1 = xp1 + (s + 1) * 32;
            a00 = *(const float4*)p0; a01 = *(const float4*)(p0 + 4);
            a10 = *(const float4*)p1; a11 = *(const float4*)(p1 + 4);
        }
        const char* wp = wbase + ((s * 64 + q * 16) ^ xr);
        #pragma unroll
        for (int j = 0; j < 8; j++) {
            bf16x8 bv = *(const bf16x8*)(wp + j * 8192);
            // swapped operands: D[n][m] -> regs span 4 consecutive n
            acc[0][j] = __builtin_amdgcn_mfma_f32_16x16x32_bf16(bv, af0, acc[0][j], 0, 0, 0);
            acc[1][j] = __builtin_amdgcn_mfma_f32_16x16x32_bf16(bv, af1, acc[1][j], 0, 0, 0);
        }
    }

    // epilogue: lane holds h[m][n..n+3] per (i,j) -> packed 8B stores
    #pragma unroll
    for (int i = 0; i < 2; i++) {
        int m = m0 + i * 16 + r;            // D col = lane&15 = x row
        if (m < N_NODES) {
            #pragma unroll
            for (int j = 0; j < 8; j++) {
                int n = wc * 128 + j * 16 + q * 4;   // D rows = n, reg spans 4
                *(ushort4*)(h + (size_t)m * WIDTH + n) = pack4(acc[i][j]);
            }
        }
    }
}

// ---------------------------------------------------------------------------
// Fused gather + self-loop + bias + LayerNorm + ReLU. (unchanged)
// One wave per dst node; lane l owns cols 4l..4l+3 (uint2 per row).
// Edge indices + weights are wave-uniform -> scalar pipe; VALU does only
// unpack + FMA. Unconditional 8-wide batches (lanes >= cd contribute exact
// +0.0 from L1-hot row 0). Record layout: rec[d*64] = poison-rebased count,
// rec[d*64+1..] = src slots.
// ---------------------------------------------------------------------------
__global__ __launch_bounds__(256) void gather_ln(const __hip_bfloat16* __restrict__ h,
                                                 const int* __restrict__ rec,
                                                 const float* __restrict__ b,
                                                 const float* __restrict__ gamma,
                                                 const float* __restrict__ beta,
                                                 float* __restrict__ out) {
    const int lane = threadIdx.x & 63;
    const int d    = blockIdx.x * 4 + (threadIdx.x >> 6);
    const int du   = __builtin_amdgcn_readfirstlane(d);   // force SGPR

    const uint2* hrows = (const uint2*)h;        // 64 uint2 per row
    const int cdt  = rec[du * RECW] - POISON_I;  // true degree (scalar load)
    const int cd   = min(cdt, SLOTS);            // slots to read
    const float dv = rsqrtf((float)(cdt + 1));
    const int base = du * RECW + 1;

    uint2 hv = hrows[(size_t)d * 64 + lane];
    float a0 = dv * bf_lo(hv.x), a1 = dv * bf_hi(hv.x);
    float a2 = dv * bf_lo(hv.y), a3 = dv * bf_hi(hv.y);

    for (int qq = 0; qq < cd; qq += 8) {
        int   sq[8]; float wq[8]; uint2 ri[8];
        #pragma unroll
        for (int u = 0; u < 8; u++) {
            int idx = qq + u;
            int s = rec[base + idx];             // s_load; garbage if idx>=cd
            s = (idx < cd) ? s : 0;              // s_cselect -> safe index
            sq[u] = s;
            int cs = rec[s * RECW] - POISON_I;   // src degree, rebased
            wq[u] = (idx < cd) ? rsqrtf((float)(cs + 1)) : 0.0f;
        }
        #pragma unroll
        for (int u = 0; u < 8; u++)
            ri[u] = hrows[(size_t)sq[u] * 64 + lane];
        #pragma unroll
        for (int u = 0; u < 8; u++) {
            a0 += wq[u] * bf_lo(ri[u].x); a1 += wq[u] * bf_hi(ri[u].x);
            a2 += wq[u] * bf_lo(ri[u].y); a3 += wq[u] * bf_hi(ri[u].y);
        }
    }

    float4 bv = *(const float4*)(b + lane * 4);
    float v0 = bv.x + dv * a0;
    float v1 = bv.y + dv * a1;
    float v2 = bv.z + dv * a2;
    float v3 = bv.w + dv * a3;

    float s1 = v0 + v1 + v2 + v3;
    float s2 = v0 * v0 + v1 * v1 + v2 * v2 + v3 * v3;
    #pragma unroll
    for (int off = 32; off > 0; off >>= 1) {
        s1 += __shfl_xor(s1, off, 64);
        s2 += __shfl_xor(s2, off, 64);
    }
    float mu   = s1 * (1.0f / 256.0f);
    float var  = s2 * (1.0f / 256.0f) - mu * mu;
    float rstd = rsqrtf(var + LN_EPS);

    float4 gv = *(const float4*)(gamma + lane * 4);
    float4 bt = *(const float4*)(beta + lane * 4);
    float4 y;
    y.x = fmaxf((v0 - mu) * rstd * gv.x + bt.x, 0.0f);
    y.y = fmaxf((v1 - mu) * rstd * gv.y + bt.y, 0.0f);
    y.z = fmaxf((v2 - mu) * rstd * gv.z + bt.z, 0.0f);
    y.w = fmaxf((v3 - mu) * rstd * gv.w + bt.w, 0.0f);
    *(float4*)(out + (size_t)d * WIDTH + lane * 4) = y;
}

// ---------------------------------------------------------------------------
extern "C" void kernel_launch(void* const* d_in, const int* in_sizes, int n_in,
                              void* d_out, int out_size, void* d_ws, size_t ws_size,
                              hipStream_t stream) {
    const float* x     = (const float*)d_in[0];
    const int*   ei    = (const int*)d_in[1];   // [2, E] flat: src then dst
    const float* W     = (const float*)d_in[2];
    const float* b     = (const float*)d_in[3];
    const float* gamma = (const float*)d_in[4];
    const float* beta  = (const float*)d_in[5];
    float* out = (float*)d_out;

    const int* src = ei;
    const int* dst = ei + N_EDGES;

    // workspace layout (4-byte word offsets):
    //   h    [0, 6400000)                      bf16, 12.8M elems (25.6 MB)
    //   rec  [6400000, 6400000+3200000+256)    per-node 256B records:
    //        rec[d*64] = atomic degree counter (poison-rebased, no memset!)
    //        rec[d*64+1 .. +63] = src slots; +256 words tail pad for the
    //        gather's unconditional 8-wide overread past the last record.
    float* wsf = (float*)d_ws;
    __hip_bfloat16* h   = (__hip_bfloat16*)wsf;
    int*            rec = (int*)(wsf + 6400000);   // byte off 25.6e6, 256B-aligned

    // Split dispatches (attribution round): per-kernel dur in rocprof.
    fill_rec<<<306, 256, 0, stream>>>(src, dst, rec);            // 306*256 >= 78125
    gemm<<<GEMM_BLKS, 1024, 0, stream>>>(x, W, h);
    gather_ln<<<N_NODES / 4, 256, 0, stream>>>(h, rec, b, gamma, beta, out);
}

// Round 6
// 183.141 us; speedup vs baseline: 1.0021x; 1.0021x over previous
//
#include <hip/hip_runtime.h>
#include <hip/hip_bf16.h>

#define N_NODES 50000
#define N_EDGES 312500
#define WIDTH   256
#define LN_EPS  1e-5f
#define RECW    64      // ints per node record: [cnt | 63 src slots] = 256B
#define SLOTS   63      // capacity; degrees ~Poisson(6.25), max ~30
#define GEMM_BLKS 196   // 196 blocks x 256 rows = 50176 >= 50000
#define POISON_I  ((int)0xAAAAAAAAu)  // harness re-poisons d_ws to 0xAA before EVERY
                                      // launch (documented contract) -> cnt baseline

typedef __attribute__((ext_vector_type(8))) short bf16x8;
typedef __attribute__((ext_vector_type(4))) float f32x4;

__device__ __forceinline__ float bf_lo(unsigned u) { return __uint_as_float(u << 16); }
__device__ __forceinline__ float bf_hi(unsigned u) { return __uint_as_float(u & 0xffff0000u); }

__device__ __forceinline__ bf16x8 cvt8(float4 a, float4 b) {
    union { __hip_bfloat16 hh[8]; bf16x8 v; } u;
    u.hh[0] = __float2bfloat16(a.x); u.hh[1] = __float2bfloat16(a.y);
    u.hh[2] = __float2bfloat16(a.z); u.hh[3] = __float2bfloat16(a.w);
    u.hh[4] = __float2bfloat16(b.x); u.hh[5] = __float2bfloat16(b.y);
    u.hh[6] = __float2bfloat16(b.z); u.hh[7] = __float2bfloat16(b.w);
    return u.v;
}

__device__ __forceinline__ ushort4 pack4(f32x4 a) {
    union { __hip_bfloat16 hh[4]; ushort4 v; } u;
    u.hh[0] = __float2bfloat16(a[0]); u.hh[1] = __float2bfloat16(a[1]);
    u.hh[2] = __float2bfloat16(a[2]); u.hh[3] = __float2bfloat16(a[3]);
    return u.v;
}

// ---------------------------------------------------------------------------
// R4 attribution: gather_ln = 46us (the top kernel; FETCH 103MB, VALU 34%,
// occ 59% -> L2-fill-traffic bound). gemm/fill each < 45us (below top-5).
// R5/R6: (1) compact dinv[] weight table (200KB, L2-resident) computed in
// gemm's tail -- kills the scattered rec[s*64] degree reads (4B useful per
// 128B line, ~30MB of fills); (2) non-temporal out stores (51MB streaming
// write was thrashing the 4MB/XCD L2 and evicting h rows). R6 = R5 with
// the nontemporal store fixed to use the clang ext_vector type (the
// builtin rejects HIP_vector_type float4).
// ---------------------------------------------------------------------------

// ---------------- bucket fill: 4 edges/thread, ILP 4, no LDS ----------------
__global__ __launch_bounds__(256) void fill_rec(const int* __restrict__ src,
                                                const int* __restrict__ dst,
                                                int* __restrict__ rec) {
    int gid = blockIdx.x * 256 + threadIdx.x;
    if (gid < N_EDGES / 4) {                // 312500 = 4*78125 exactly
        int4 d4 = *(const int4*)(dst + gid * 4);
        int4 s4 = *(const int4*)(src + gid * 4);
        int dd[4] = {d4.x, d4.y, d4.z, d4.w};
        int ss[4] = {s4.x, s4.y, s4.z, s4.w};
        #pragma unroll
        for (int u = 0; u < 4; u++) {
            int pos = atomicAdd(&rec[dd[u] * RECW], 1) - POISON_I;  // rebase poison
            rec[dd[u] * RECW + 1 + min(pos, SLOTS - 1)] = ss[u];
        }
    }
}

// ---------------- GEMM: 256 rows x 256 cols per block ----------------
// W resident in LDS as bf16 (128 KiB), staged once, ONE barrier, zero
// barriers in K-loop; x streamed global->reg with 1-step prefetch.
// Tail (blocks 0..48): compute dinv[n] = rsqrt(deg_n+1) into a compact
// 200KB table (fill_rec is stream-ordered before gemm, so rec is final).
__global__ __launch_bounds__(1024, 4) void gemm(const float* __restrict__ x,
                                                const float* __restrict__ W,
                                                __hip_bfloat16* __restrict__ h,
                                                const int* __restrict__ rec,
                                                float* __restrict__ dinv) {
    const int blk = blockIdx.x;
    const int t   = threadIdx.x;
    __shared__ short Wl[65536];
    const int lane = t & 63;
    const int wv   = t >> 6;               // 0..15
    const int wr   = wv & 7;               // row strip (32 rows)
    const int wc   = wv >> 3;              // col half (128 cols)
    const int r    = lane & 15;
    const int q    = lane >> 4;
    const int xr   = (r & 7) << 4;         // read-side XOR (n&7 == r&7)

    // issue s=0 x prefetch BEFORE W staging (hide HBM latency under stage)
    const int m0 = blk * 256 + wr * 32;
    const int g0 = min(m0 + r,      N_NODES - 1);   // clamp; garbage never stored
    const int g1 = min(m0 + 16 + r, N_NODES - 1);
    const float* xp0 = x + (size_t)g0 * WIDTH + q * 8;
    const float* xp1 = x + (size_t)g1 * WIDTH + q * 8;
    float4 a00 = *(const float4*)xp0;
    float4 a01 = *(const float4*)(xp0 + 4);
    float4 a10 = *(const float4*)xp1;
    float4 a11 = *(const float4*)(xp1 + 4);

    // ---- stage W -> LDS (bf16, swizzled). 64 floats/thread, 8 iters. ----
    #pragma unroll
    for (int it = 0; it < 8; it++) {
        int f0 = (it * 1024 + t) * 8;      // linear float index = n*256 + k
        int n  = f0 >> 8;
        int k0 = f0 & 255;
        const float* wp = W + f0;
        float4 wa = *(const float4*)wp;
        float4 wb = *(const float4*)(wp + 4);
        int off = (n * 512 + k0 * 2) ^ ((n & 7) << 4);   // full-offset XOR: safe
        *(bf16x8*)((char*)Wl + off) = cvt8(wa, wb);
    }
    __syncthreads();                        // the ONLY barrier

    f32x4 acc[2][8];
    #pragma unroll
    for (int i = 0; i < 2; i++)
        #pragma unroll
        for (int j = 0; j < 8; j++)
            #pragma unroll
            for (int rr = 0; rr < 4; rr++) acc[i][j][rr] = 0.0f;

    // + r*512, + wc*65536 are multiples of 512 -> adding AFTER the bits-4..6
    // XOR cannot carry; j*8192 likewise.
    const char* wbase = (const char*)Wl + wc * 65536 + r * 512;

    #pragma unroll
    for (int s = 0; s < 8; s++) {
        bf16x8 af0 = cvt8(a00, a01);
        bf16x8 af1 = cvt8(a10, a11);
        if (s < 7) {                        // prefetch next k-step
            const float* p0 = xp0 + (s + 1) * 32;
            const float* p1 = xp1 + (s + 1) * 32;
            a00 = *(const float4*)p0; a01 = *(const float4*)(p0 + 4);
            a10 = *(const float4*)p1; a11 = *(const float4*)(p1 + 4);
        }
        const char* wp = wbase + ((s * 64 + q * 16) ^ xr);
        #pragma unroll
        for (int j = 0; j < 8; j++) {
            bf16x8 bv = *(const bf16x8*)(wp + j * 8192);
            // swapped operands: D[n][m] -> regs span 4 consecutive n
            acc[0][j] = __builtin_amdgcn_mfma_f32_16x16x32_bf16(bv, af0, acc[0][j], 0, 0, 0);
            acc[1][j] = __builtin_amdgcn_mfma_f32_16x16x32_bf16(bv, af1, acc[1][j], 0, 0, 0);
        }
    }

    // epilogue: lane holds h[m][n..n+3] per (i,j) -> packed 8B stores
    #pragma unroll
    for (int i = 0; i < 2; i++) {
        int m = m0 + i * 16 + r;            // D col = lane&15 = x row
        if (m < N_NODES) {
            #pragma unroll
            for (int j = 0; j < 8; j++) {
                int n = wc * 128 + j * 16 + q * 4;   // D rows = n, reg spans 4
                *(ushort4*)(h + (size_t)m * WIDTH + n) = pack4(acc[i][j]);
            }
        }
    }

    // ---- dinv tail: blocks 0..48 compute the compact weight table ----
    int gid = blk * 1024 + t;
    if (gid < N_NODES) {
        int c = rec[gid * RECW] - POISON_I;          // poison-rebased degree
        dinv[gid] = rsqrtf((float)(c + 1));
    }
}

// ---------------------------------------------------------------------------
// Fused gather + self-loop + bias + LayerNorm + ReLU.
// One wave per dst node; lane l owns cols 4l..4l+3 (uint2 per row).
// Edge indices + weights are wave-uniform -> scalar pipe; VALU does only
// unpack + FMA. Unconditional 8-wide batches (lanes >= cd contribute exact
// +0.0 from L1-hot row 0). Neighbor weights now come from the compact
// dinv[] table (200KB, L2-resident) instead of scattered rec[s*64] lines.
// out stores are non-temporal: final data, keep it out of L2 so h rows
// stay resident.
// ---------------------------------------------------------------------------
__global__ __launch_bounds__(256) void gather_ln(const __hip_bfloat16* __restrict__ h,
                                                 const int* __restrict__ rec,
                                                 const float* __restrict__ dinv,
                                                 const float* __restrict__ b,
                                                 const float* __restrict__ gamma,
                                                 const float* __restrict__ beta,
                                                 float* __restrict__ out) {
    const int lane = threadIdx.x & 63;
    const int d    = blockIdx.x * 4 + (threadIdx.x >> 6);
    const int du   = __builtin_amdgcn_readfirstlane(d);   // force SGPR

    const uint2* hrows = (const uint2*)h;        // 64 uint2 per row
    const int cdt  = rec[du * RECW] - POISON_I;  // true degree (scalar load)
    const int cd   = min(cdt, SLOTS);            // slots to read
    const float dv = rsqrtf((float)(cdt + 1));
    const int base = du * RECW + 1;

    uint2 hv = hrows[(size_t)d * 64 + lane];
    float a0 = dv * bf_lo(hv.x), a1 = dv * bf_hi(hv.x);
    float a2 = dv * bf_lo(hv.y), a3 = dv * bf_hi(hv.y);

    for (int qq = 0; qq < cd; qq += 8) {
        int   sq[8]; float wq[8]; uint2 ri[8];
        #pragma unroll
        for (int u = 0; u < 8; u++) {
            int idx = qq + u;
            int s = rec[base + idx];             // s_load; garbage if idx>=cd
            s = (idx < cd) ? s : 0;              // s_cselect -> safe index
            sq[u] = s;
            wq[u] = (idx < cd) ? dinv[s] : 0.0f; // compact table, L2-hot
        }
        #pragma unroll
        for (int u = 0; u < 8; u++)
            ri[u] = hrows[(size_t)sq[u] * 64 + lane];
        #pragma unroll
        for (int u = 0; u < 8; u++) {
            a0 += wq[u] * bf_lo(ri[u].x); a1 += wq[u] * bf_hi(ri[u].x);
            a2 += wq[u] * bf_lo(ri[u].y); a3 += wq[u] * bf_hi(ri[u].y);
        }
    }

    float4 bv = *(const float4*)(b + lane * 4);
    float v0 = bv.x + dv * a0;
    float v1 = bv.y + dv * a1;
    float v2 = bv.z + dv * a2;
    float v3 = bv.w + dv * a3;

    float s1 = v0 + v1 + v2 + v3;
    float s2 = v0 * v0 + v1 * v1 + v2 * v2 + v3 * v3;
    #pragma unroll
    for (int off = 32; off > 0; off >>= 1) {
        s1 += __shfl_xor(s1, off, 64);
        s2 += __shfl_xor(s2, off, 64);
    }
    float mu   = s1 * (1.0f / 256.0f);
    float var  = s2 * (1.0f / 256.0f) - mu * mu;
    float rstd = rsqrtf(var + LN_EPS);

    float4 gv = *(const float4*)(gamma + lane * 4);
    float4 bt = *(const float4*)(beta + lane * 4);
    f32x4 y;
    y[0] = fmaxf((v0 - mu) * rstd * gv.x + bt.x, 0.0f);
    y[1] = fmaxf((v1 - mu) * rstd * gv.y + bt.y, 0.0f);
    y[2] = fmaxf((v2 - mu) * rstd * gv.z + bt.z, 0.0f);
    y[3] = fmaxf((v3 - mu) * rstd * gv.w + bt.w, 0.0f);
    // clang ext_vector (f32x4) is accepted by the builtin; HIP float4 is not
    __builtin_nontemporal_store(y, (f32x4*)(out + (size_t)d * WIDTH + lane * 4));
}

// ---------------------------------------------------------------------------
extern "C" void kernel_launch(void* const* d_in, const int* in_sizes, int n_in,
                              void* d_out, int out_size, void* d_ws, size_t ws_size,
                              hipStream_t stream) {
    const float* x     = (const float*)d_in[0];
    const int*   ei    = (const int*)d_in[1];   // [2, E] flat: src then dst
    const float* W     = (const float*)d_in[2];
    const float* b     = (const float*)d_in[3];
    const float* gamma = (const float*)d_in[4];
    const float* beta  = (const float*)d_in[5];
    float* out = (float*)d_out;

    const int* src = ei;
    const int* dst = ei + N_EDGES;

    // workspace layout (4-byte word offsets), total 9,650,000 words = 38.6MB
    // (<= previously-proven high-water mark 9,650,048):
    //   h    [0, 6400000)              bf16, 12.8M elems (25.6 MB)
    //   rec  [6400000, 9600000)        per-node 256B records:
    //        rec[d*64] = atomic degree counter (poison-rebased, no memset!)
    //        rec[d*64+1 .. +63] = src slots
    //   dinv [9600000, 9650000)        compact rsqrt(deg+1) table (200KB);
    //        gather's <=7-word unconditional tail overread past rec lands
    //        here -- mapped memory, values discarded by the idx<cd select.
    float* wsf = (float*)d_ws;
    __hip_bfloat16* h    = (__hip_bfloat16*)wsf;
    int*            rec  = (int*)(wsf + 6400000);
    float*          dinv = wsf + 9600000;

    fill_rec<<<306, 256, 0, stream>>>(src, dst, rec);            // 306*256 >= 78125
    gemm<<<GEMM_BLKS, 1024, 0, stream>>>(x, W, h, rec, dinv);
    gather_ln<<<N_NODES / 4, 256, 0, stream>>>(h, rec, dinv, b, gamma, beta, out);
}

// Round 7
// 166.982 us; speedup vs baseline: 1.0991x; 1.0968x over previous
//
#include <hip/hip_runtime.h>
#include <hip/hip_bf16.h>

#define N_NODES 50000
#define N_EDGES 312500
#define WIDTH   256
#define LN_EPS  1e-5f
#define CAP     64      // per-node bucket capacity; degrees ~Poisson(6.25), max ~30
#define GEMM_BLKS 1564  // 782 row-tiles x 2 col-tiles
#define FILL_BLKS 1221  // ceil(312500/256)
#define POISON_I  ((int)0xAAAAAAAAu)  // harness re-poisons d_ws to 0xAA before EVERY
                                      // launch (documented contract) -> cnt[] baseline

typedef __attribute__((ext_vector_type(8))) short bf16x8;
typedef __attribute__((ext_vector_type(4))) float f32x4;

__device__ __forceinline__ float bf_lo(unsigned u) { return __uint_as_float(u << 16); }
__device__ __forceinline__ float bf_hi(unsigned u) { return __uint_as_float(u & 0xffff0000u); }

__device__ __forceinline__ bf16x8 cvt8(float4 a, float4 b) {
    union { __hip_bfloat16 hh[8]; bf16x8 v; } u;
    u.hh[0] = __float2bfloat16(a.x); u.hh[1] = __float2bfloat16(a.y);
    u.hh[2] = __float2bfloat16(a.z); u.hh[3] = __float2bfloat16(a.w);
    u.hh[4] = __float2bfloat16(b.x); u.hh[5] = __float2bfloat16(b.y);
    u.hh[6] = __float2bfloat16(b.z); u.hh[7] = __float2bfloat16(b.w);
    return u.v;
}

// ---------------------------------------------------------------------------
// R6 post-mortem: the 42us/256MiB fillBufferAligned rows are the HARNESS
// POISON -- a fixed floor per iteration, and the top-5 cutoff. Dispatch-count
// arithmetic: R0 (2 dispatches)=167.3 vs R4/R6 (3 dispatches)=183.3 -> launch
// gaps ~8us/boundary. gather_ln fell below the 42us cutoff in R6 (<41.6, was
// 46 in R4) -> NT-store/compact-count direction works.
// R7: re-fuse to the PROVEN 2-dispatch structure (R0 combo: 64x128 MFMA GEMM
// + compact-cnt bucket fill, 44-46us measured) + keep the one proven gather
// win (non-temporal out stores; count reads from compact 200KB cnt[] are
// L2-hot, so no dinv precompute needed). Single delta vs R0 = NT store.
// cnt[] is NOT zeroed: counts start at POISON_I and are rebased.
// History: no-LDS=69us; 128x128 single-buf=44us; grid-barrier fusion=114us;
// W-resident 1024-thr gemm: equal in combo (46.8) and NOT faster split.
// ---------------------------------------------------------------------------
__global__ __launch_bounds__(256, 4) void gemm_fill(const float* __restrict__ x,
                                                    const float* __restrict__ W,
                                                    __hip_bfloat16* __restrict__ h,
                                                    const int* __restrict__ src,
                                                    const int* __restrict__ dst,
                                                    int* __restrict__ cnt,
                                                    int* __restrict__ bucket) {
    const int blk = blockIdx.x;
    if (blk >= GEMM_BLKS) {
        // ---------------- bucket fill ----------------
        int i = (blk - GEMM_BLKS) * 256 + threadIdx.x;
        if (i < N_EDGES) {
            int d = dst[i];
            int pos = atomicAdd(&cnt[d], 1) - POISON_I;   // rebase from poison
            bucket[d * CAP + min(pos, CAP - 1)] = src[i];
        }
        return;
    }

    // ---------------- GEMM 64x128 ----------------
    __shared__ short As[64][72];
    __shared__ short Bs[128][72];
    const int t    = threadIdx.x;
    const int lane = t & 63;
    const int wv   = t >> 6;
    const int wm   = wv & 1;          // row half (32 rows)
    const int wn   = wv >> 1;         // col half (64 cols)
    const int lrow = lane & 15;
    const int quad = lane >> 4;
    const int mrow0 = (blk >> 1) * 64;
    const int ncol0 = (blk & 1) * 128;

    f32x4 acc[2][4];
    #pragma unroll
    for (int i = 0; i < 2; i++)
        #pragma unroll
        for (int j = 0; j < 4; j++)
            #pragma unroll
            for (int r = 0; r < 4; r++) acc[i][j][r] = 0.0f;

    const int sr = t >> 3;            // 0..31 staging row
    const int sg = t & 7;             // 0..7  16B group

    float4 pa0[2], pa1[2], pb0[4], pb1[4];
    auto load_chunk = [&](int k0) {
        #pragma unroll
        for (int p = 0; p < 2; p++) {
            int r  = p * 32 + sr;
            int gr = min(mrow0 + r, N_NODES - 1);   // clamp; garbage rows never stored
            const float* xp = x + (size_t)gr * WIDTH + k0 + sg * 8;
            pa0[p] = *(const float4*)xp;
            pa1[p] = *(const float4*)(xp + 4);
        }
        #pragma unroll
        for (int p = 0; p < 4; p++) {
            int gn = ncol0 + p * 32 + sr;            // always < 256
            const float* wp = W + (size_t)gn * WIDTH + k0 + sg * 8;
            pb0[p] = *(const float4*)wp;
            pb1[p] = *(const float4*)(wp + 4);
        }
    };

    load_chunk(0);
    for (int kc = 0; kc < 4; kc++) {
        if (kc) __syncthreads();                     // prev chunk's reads done
        #pragma unroll
        for (int p = 0; p < 2; p++)
            *(bf16x8*)&As[p * 32 + sr][sg * 8] = cvt8(pa0[p], pa1[p]);
        #pragma unroll
        for (int p = 0; p < 4; p++)
            *(bf16x8*)&Bs[p * 32 + sr][sg * 8] = cvt8(pb0[p], pb1[p]);
        __syncthreads();
        if (kc < 3) load_chunk((kc + 1) * 64);       // prefetch next chunk

        #pragma unroll
        for (int s = 0; s < 2; s++) {
            bf16x8 af[2], bfr[4];
            #pragma unroll
            for (int i = 0; i < 2; i++)
                af[i] = *(const bf16x8*)&As[wm * 32 + i * 16 + lrow][s * 32 + quad * 8];
            #pragma unroll
            for (int j = 0; j < 4; j++)
                bfr[j] = *(const bf16x8*)&Bs[wn * 64 + j * 16 + lrow][s * 32 + quad * 8];
            #pragma unroll
            for (int i = 0; i < 2; i++)
                #pragma unroll
                for (int j = 0; j < 4; j++)
                    acc[i][j] = __builtin_amdgcn_mfma_f32_16x16x32_bf16(
                        af[i], bfr[j], acc[i][j], 0, 0, 0);
        }
    }

    #pragma unroll
    for (int i = 0; i < 2; i++) {
        #pragma unroll
        for (int j = 0; j < 4; j++) {
            int col = ncol0 + wn * 64 + j * 16 + lrow;
            #pragma unroll
            for (int r = 0; r < 4; r++) {
                int gr = mrow0 + wm * 32 + i * 16 + quad * 4 + r;
                if (gr < N_NODES)
                    h[(size_t)gr * WIDTH + col] = __float2bfloat16(acc[i][j][r]);
            }
        }
    }
}

// ---------------------------------------------------------------------------
// Fused gather + self-loop + bias + LayerNorm + ReLU.
// One wave per dst node; lane l owns cols 4l..4l+3 (uint2 per row).
// Edge indices + weights are wave-uniform -> scalar pipe (s_load/s_cselect);
// VALU does only unpack + FMA. Unconditional 8-wide batches (lanes >= cd
// contribute exact +0.0 from L1-hot row 0). Degrees rebased from poison;
// cnt[] is a compact 200KB table -> scattered cnt[s] reads are L2-hot.
// R7: out stores are NON-TEMPORAL (final data; keeps the 51MB streaming
// write from evicting h rows -- gather_ln dropped below the 42us poison
// cutoff with this in R6).
// ---------------------------------------------------------------------------
__global__ __launch_bounds__(256) void gather_ln(const __hip_bfloat16* __restrict__ h,
                                                 const int* __restrict__ cnt,
                                                 const int* __restrict__ bucket,
                                                 const float* __restrict__ b,
                                                 const float* __restrict__ gamma,
                                                 const float* __restrict__ beta,
                                                 float* __restrict__ out) {
    const int lane = threadIdx.x & 63;
    const int d    = blockIdx.x * 4 + (threadIdx.x >> 6);
    const int du   = __builtin_amdgcn_readfirstlane(d);   // force SGPR

    const uint2* hrows = (const uint2*)h;        // 64 uint2 per row
    const int cd = min(cnt[du] - POISON_I, CAP); // scalar load, rebased
    const float dv = rsqrtf((float)(cd + 1));
    const int base = du * CAP;

    uint2 hv = hrows[(size_t)d * 64 + lane];
    float a0 = dv * bf_lo(hv.x), a1 = dv * bf_hi(hv.x);
    float a2 = dv * bf_lo(hv.y), a3 = dv * bf_hi(hv.y);

    for (int q = 0; q < cd; q += 8) {
        int   sq[8]; float wq[8]; uint2 ri[8];
        #pragma unroll
        for (int u = 0; u < 8; u++) {
            int idx = q + u;
            int s = bucket[base + idx];          // s_load; garbage if idx>=cd
            s = (idx < cd) ? s : 0;              // s_cselect -> safe index
            sq[u] = s;
            int cs = cnt[s] - POISON_I;          // s_load, compact table (L2-hot)
            wq[u] = (idx < cd) ? rsqrtf((float)(cs + 1)) : 0.0f;
        }
        #pragma unroll
        for (int u = 0; u < 8; u++)
            ri[u] = hrows[(size_t)sq[u] * 64 + lane];
        #pragma unroll
        for (int u = 0; u < 8; u++) {
            a0 += wq[u] * bf_lo(ri[u].x); a1 += wq[u] * bf_hi(ri[u].x);
            a2 += wq[u] * bf_lo(ri[u].y); a3 += wq[u] * bf_hi(ri[u].y);
        }
    }

    float4 bv = *(const float4*)(b + lane * 4);
    float v0 = bv.x + dv * a0;
    float v1 = bv.y + dv * a1;
    float v2 = bv.z + dv * a2;
    float v3 = bv.w + dv * a3;

    float s1 = v0 + v1 + v2 + v3;
    float s2 = v0 * v0 + v1 * v1 + v2 * v2 + v3 * v3;
    #pragma unroll
    for (int off = 32; off > 0; off >>= 1) {
        s1 += __shfl_xor(s1, off, 64);
        s2 += __shfl_xor(s2, off, 64);
    }
    float mu   = s1 * (1.0f / 256.0f);
    float var  = s2 * (1.0f / 256.0f) - mu * mu;
    float rstd = rsqrtf(var + LN_EPS);

    float4 gv = *(const float4*)(gamma + lane * 4);
    float4 bt = *(const float4*)(beta + lane * 4);
    f32x4 y;
    y[0] = fmaxf((v0 - mu) * rstd * gv.x + bt.x, 0.0f);
    y[1] = fmaxf((v1 - mu) * rstd * gv.y + bt.y, 0.0f);
    y[2] = fmaxf((v2 - mu) * rstd * gv.z + bt.z, 0.0f);
    y[3] = fmaxf((v3 - mu) * rstd * gv.w + bt.w, 0.0f);
    // clang ext_vector (f32x4) is accepted by the builtin; HIP float4 is not
    __builtin_nontemporal_store(y, (f32x4*)(out + (size_t)d * WIDTH + lane * 4));
}

// ---------------------------------------------------------------------------
extern "C" void kernel_launch(void* const* d_in, const int* in_sizes, int n_in,
                              void* d_out, int out_size, void* d_ws, size_t ws_size,
                              hipStream_t stream) {
    const float* x     = (const float*)d_in[0];
    const int*   ei    = (const int*)d_in[1];   // [2, E] flat: src then dst
    const float* W     = (const float*)d_in[2];
    const float* b     = (const float*)d_in[3];
    const float* gamma = (const float*)d_in[4];
    const float* beta  = (const float*)d_in[5];
    float* out = (float*)d_out;

    const int* src = ei;
    const int* dst = ei + N_EDGES;

    // workspace layout (4-byte word offsets):
    //   h       [0, 6400000)             bf16, 12.8M elems (6.4M words)
    //   cnt     [6400000, 6450000)       per-dst degree, poison-rebased (no memset!)
    //   bucket  [6450048, 6450048+3.2M)  int src per slot, CAP=64 per node
    float* wsf = (float*)d_ws;
    __hip_bfloat16* h      = (__hip_bfloat16*)wsf;
    int*            cnt    = (int*)(wsf + 6400000);
    int*            bucket = (int*)(wsf + 6450048);

    // 1) combo: GEMM blocks + bucket-fill blocks in one dispatch
    gemm_fill<<<GEMM_BLKS + FILL_BLKS, 256, 0, stream>>>(x, W, h, src, dst, cnt, bucket);

    // 2) fused gather + LN + ReLU (NT out stores)
    gather_ln<<<N_NODES / 4, 256, 0, stream>>>(h, cnt, bucket, b, gamma, beta, out);
}